// Round 10
// baseline (480.310 us; speedup 1.0000x reference)
//
#include <hip/hip_runtime.h>

#define N_PTS 131072
#define DIM   64
#define CELLS 256
#define EPSF  1e-8f
#define WS_ALPHA 1024   // alpha array offset (floats) in d_ws

// ---------------------------------------------------------------------------
// prep: per-cell norms, gate=sigmoid(gate_logits), cscale=-log2(e)/temp
// ws: [0..255]=||P||^2 [256..511]=||G||^2 [512..767]=gate [768]=cscale
// ---------------------------------------------------------------------------
__global__ void prep_kernel(const float* __restrict__ prototypes,
                            const float* __restrict__ grid_pos,
                            const float* __restrict__ gate_logits,
                            const float* __restrict__ temp_raw,
                            float* __restrict__ ws) {
    const int c = threadIdx.x;
    const float* p = prototypes + c * DIM;
    const float* g = grid_pos   + c * DIM;
    float pn = 0.f, gn = 0.f;
#pragma unroll
    for (int k = 0; k < DIM; ++k) {
        pn = fmaf(p[k], p[k], pn);
        gn = fmaf(g[k], g[k], gn);
    }
    ws[c]             = pn;
    ws[CELLS + c]     = gn;
    ws[2 * CELLS + c] = 1.f / (1.f + expf(-gate_logits[c]));
    if (c == 0) {
        float sg   = 1.f / (1.f + expf(-temp_raw[0]));
        float temp = sg * (1.f - 0.001f) + 0.001f;
        ws[3 * CELLS] = -1.4426950408889634f / temp;  // -log2(e)/temp
    }
}

// ---------------------------------------------------------------------------
// dist v2: block tile 128 pts x 128 cells (2 chunks), k-panels of 32.
// Thread (pr=t>>4, cr=t&15): pts {4pr+i, 64+4pr+i}, cells {4cr+j, 64+4cr+j}
// -> every fragment read = 16 block-addresses spread evenly over bank groups
// (the R7 measured-zero-conflict mapping). 8x8 register tile = 128 accums,
// 0.75 B LDS per FMA (below the b128 pipe balance point).
// LDS (floats): xT[64][128]=8192 | PT[32][128]=4096 | GT[32][128]=4096 |
//               xnL[128] | s1L[2][128] | sgL[2][128]   (68096 B total)
// ttile [128][64] overlays PT+GT between chunks for coalesced w stores.
// ---------------------------------------------------------------------------
__global__ __launch_bounds__(256, 2)
void dist_kernel(const float* __restrict__ x,
                 const float* __restrict__ P,
                 const float* __restrict__ G,
                 const float* __restrict__ ws,
                 float* __restrict__ w_out,
                 float* __restrict__ alpha_out) {
    extern __shared__ float lds[];
    float* xT  = lds;              // [64][128]
    float* PT  = lds + 8192;       // [32][128]
    float* GT  = lds + 12288;      // [32][128]
    float* xnL = lds + 16384;      // [128]
    float* s1L = lds + 16512;      // [2][128]
    float* sgL = lds + 16768;      // [2][128]
    float* ttile = PT;             // [128][64] overlay (PT+GT dead)

    const int t  = threadIdx.x;
    const int pr = t >> 4;
    const int cr = t & 15;
    const int pbase = blockIdx.x * 128;

#define PTS(i) ((i) < 4 ? 4 * pr + (i) : 64 + 4 * pr + ((i) - 4))

    // ---- stage xT (transpose+swizzle) + ||x||^2 partials into PT scratch ---
    {
        const int pt   = t & 127;
        const int half = t >> 7;
        const float4* xp = reinterpret_cast<const float4*>(
            x + (size_t)(pbase + pt) * DIM) + half * 8;
        float xpart = 0.f;
#pragma unroll
        for (int j = 0; j < 8; ++j) {
            float4 v = xp[j];
            xpart += v.x * v.x + v.y * v.y + v.z * v.z + v.w * v.w;
#pragma unroll
            for (int jj = 0; jj < 4; ++jj) {
                const int k = 32 * half + 4 * j + jj;
                xT[k * 128 + 4 * ((pt >> 2) ^ (k & 31)) + (pt & 3)] = (&v.x)[jj];
            }
        }
        PT[half * 128 + pt] = xpart;
    }
    __syncthreads();
    if (t < 128) xnL[t] = PT[t] + PT[128 + t];
    __syncthreads();

    const float cscale = ws[3 * CELLS];

#pragma unroll 1
    for (int ch = 0; ch < 2; ++ch) {
        const int cc0 = ch * 128;
        float aP[8][8], aG[8][8];
#pragma unroll
        for (int i = 0; i < 8; ++i)
#pragma unroll
            for (int j = 0; j < 8; ++j) { aP[i][j] = 0.f; aG[i][j] = 0.f; }

#pragma unroll 1
        for (int pan = 0; pan < 2; ++pan) {
            const int k0 = pan * 32;
            // ---- stage PT/GT panel (lane->cell contiguous, k uniform) ----
            {
                const int cl = t & 127;
                const int kh = t >> 7;
                const float4* Pp = reinterpret_cast<const float4*>(
                    P + (size_t)(cc0 + cl) * DIM + k0 + 16 * kh);
                const float4* Gp = reinterpret_cast<const float4*>(
                    G + (size_t)(cc0 + cl) * DIM + k0 + 16 * kh);
#pragma unroll
                for (int j = 0; j < 4; ++j) {
                    float4 v = Pp[j];
                    float4 u = Gp[j];
#pragma unroll
                    for (int jj = 0; jj < 4; ++jj) {
                        const int kk  = 16 * kh + 4 * j + jj;
                        const int off = kk * 128 + 4 * ((cl >> 2) ^ kk) + (cl & 3);
                        PT[off] = (&v.x)[jj];
                        GT[off] = (&u.x)[jj];
                    }
                }
            }
            __syncthreads();

#pragma unroll 4
            for (int kk = 0; kk < 32; ++kk) {
                const int k = k0 + kk;
                const float4 xf0 = *reinterpret_cast<const float4*>(
                    &xT[k * 128 + 4 * (pr ^ (k & 31))]);
                const float4 xf1 = *reinterpret_cast<const float4*>(
                    &xT[k * 128 + 4 * ((16 + pr) ^ (k & 31))]);
                const float4 pf0 = *reinterpret_cast<const float4*>(
                    &PT[kk * 128 + 4 * (cr ^ kk)]);
                const float4 pf1 = *reinterpret_cast<const float4*>(
                    &PT[kk * 128 + 4 * ((16 + cr) ^ kk)]);
                const float4 gf0 = *reinterpret_cast<const float4*>(
                    &GT[kk * 128 + 4 * (cr ^ kk)]);
                const float4 gf1 = *reinterpret_cast<const float4*>(
                    &GT[kk * 128 + 4 * ((16 + cr) ^ kk)]);
#pragma unroll
                for (int i = 0; i < 4; ++i) {
                    const float a = (&xf0.x)[i];
                    const float b = (&xf1.x)[i];
#pragma unroll
                    for (int j = 0; j < 4; ++j) {
                        const float p0 = (&pf0.x)[j];
                        const float p1 = (&pf1.x)[j];
                        const float g0 = (&gf0.x)[j];
                        const float g1 = (&gf1.x)[j];
                        aP[i][j]         = fmaf(a, p0, aP[i][j]);
                        aP[i][4 + j]     = fmaf(a, p1, aP[i][4 + j]);
                        aP[4 + i][j]     = fmaf(b, p0, aP[4 + i][j]);
                        aP[4 + i][4 + j] = fmaf(b, p1, aP[4 + i][4 + j]);
                        aG[i][j]         = fmaf(a, g0, aG[i][j]);
                        aG[i][4 + j]     = fmaf(a, g1, aG[i][4 + j]);
                        aG[4 + i][j]     = fmaf(b, g0, aG[4 + i][j]);
                        aG[4 + i][4 + j] = fmaf(b, g1, aG[4 + i][4 + j]);
                    }
                }
            }
            __syncthreads();   // panel consumed (restage or ttile overlay next)
        }

        // ---- epilogue: t = exp(-(dP+dG)/temp)*gate, shuffle-reduce s1/sg ---
        const float4 pn0 = *reinterpret_cast<const float4*>(ws + cc0 + 4 * cr);
        const float4 pn1 = *reinterpret_cast<const float4*>(ws + cc0 + 64 + 4 * cr);
        const float4 gn0 = *reinterpret_cast<const float4*>(ws + CELLS + cc0 + 4 * cr);
        const float4 gn1 = *reinterpret_cast<const float4*>(ws + CELLS + cc0 + 64 + 4 * cr);
        const float4 ga0 = *reinterpret_cast<const float4*>(ws + 2 * CELLS + cc0 + 4 * cr);
        const float4 ga1 = *reinterpret_cast<const float4*>(ws + 2 * CELLS + cc0 + 64 + 4 * cr);
        float tt[8][8];
#pragma unroll
        for (int i = 0; i < 8; ++i) {
            const float xnv = xnL[PTS(i)];
            float s1 = 0.f, sg = 0.f;
#pragma unroll
            for (int j = 0; j < 8; ++j) {
                const float pnj = (j < 4) ? (&pn0.x)[j] : (&pn1.x)[j - 4];
                const float gnj = (j < 4) ? (&gn0.x)[j] : (&gn1.x)[j - 4];
                const float gaj = (j < 4) ? (&ga0.x)[j] : (&ga1.x)[j - 4];
                float dp2 = fmaf(-2.f, aP[i][j], xnv + pnj);
                float dg2 = fmaf(-2.f, aG[i][j], xnv + gnj);
                float d   = sqrtf(fmaxf(dp2, 0.f)) + sqrtf(fmaxf(dg2, 0.f));
                float e   = exp2f(d * cscale);
                s1 += e;
                float tv = e * gaj;
                sg += tv;
                tt[i][j] = tv;
            }
            s1 += __shfl_xor(s1, 1);  sg += __shfl_xor(sg, 1);
            s1 += __shfl_xor(s1, 2);  sg += __shfl_xor(sg, 2);
            s1 += __shfl_xor(s1, 4);  sg += __shfl_xor(sg, 4);
            s1 += __shfl_xor(s1, 8);  sg += __shfl_xor(sg, 8);
            if (cr == 0) { s1L[ch * 128 + PTS(i)] = s1; sgL[ch * 128 + PTS(i)] = sg; }
        }

        // ---- half A (cells 0..63 of chunk): ttile + coalesced store ----
#pragma unroll
        for (int i = 0; i < 8; ++i) {
            const int p = PTS(i);
            *reinterpret_cast<float4*>(&ttile[p * 64 + 4 * (cr ^ (p & 15))]) =
                make_float4(tt[i][0], tt[i][1], tt[i][2], tt[i][3]);
        }
        __syncthreads();
#pragma unroll
        for (int j = 0; j < 8; ++j) {
            const int f = j * 256 + t;
            const int row = f >> 4;
            const int q   = f & 15;
            float4 v = *reinterpret_cast<const float4*>(
                &ttile[row * 64 + 4 * (q ^ (row & 15))]);
            *reinterpret_cast<float4*>(
                w_out + (size_t)(pbase + row) * CELLS + cc0 + 4 * q) = v;
        }
        __syncthreads();
        // ---- half B (cells 64..127 of chunk) ----
#pragma unroll
        for (int i = 0; i < 8; ++i) {
            const int p = PTS(i);
            *reinterpret_cast<float4*>(&ttile[p * 64 + 4 * (cr ^ (p & 15))]) =
                make_float4(tt[i][4], tt[i][5], tt[i][6], tt[i][7]);
        }
        __syncthreads();
#pragma unroll
        for (int j = 0; j < 8; ++j) {
            const int f = j * 256 + t;
            const int row = f >> 4;
            const int q   = f & 15;
            float4 v = *reinterpret_cast<const float4*>(
                &ttile[row * 64 + 4 * (q ^ (row & 15))]);
            *reinterpret_cast<float4*>(
                w_out + (size_t)(pbase + row) * CELLS + cc0 + 64 + 4 * q) = v;
        }
        __syncthreads();
    }

    // ref: w1=e/(s1+eps); t1=w1*gate; s2=sum t1; w2=t1/(s2+eps)
    //   => w2 = (e*gate)*alpha, alpha = 1/((s1+eps)*(s2+eps))
    if (t < 128) {
        const float A  = s1L[t] + s1L[128 + t] + EPSF;
        const float sg = sgL[t] + sgL[128 + t];
        const float s2 = sg / A;
        alpha_out[pbase + t] = 1.f / (A * (s2 + EPSF));
    }
#undef PTS
}

// ---------------------------------------------------------------------------
// blend v2: w2 = t*alpha (write-back) and blended = w2 @ P, with T14-style
// register double-buffer prefetch: chunk c+1's global loads issue before
// chunk c's k-loop, hiding HBM latency under 32x64 FMAs.
// ---------------------------------------------------------------------------
__global__ __launch_bounds__(256, 3)
void blend_kernel(float* __restrict__ w,          // in: t, out: w2 = t*alpha
                  const float* __restrict__ P,
                  const float* __restrict__ alpha_in,
                  float* __restrict__ bl) {
    extern __shared__ float lds2[];
    float* wT = lds2;           // [32][256] (8192 floats)
    float* Pt = lds2 + 8192;    // [32][64]  (2048 floats)

    const int t  = threadIdx.x;
    const int pr = t & 31;
    const int dr = t >> 5;
    const size_t pbase = (size_t)blockIdx.x * 256;

    const float al = alpha_in[pbase + t];

    float acc[8][8];
#pragma unroll
    for (int i = 0; i < 8; ++i)
#pragma unroll
        for (int j = 0; j < 8; ++j) acc[i][j] = 0.f;

    auto LOADW = [&](float4* wr, float4* pp, int cc0) {
        const float* wrow = w + (pbase + t) * CELLS + cc0;
#pragma unroll
        for (int j = 0; j < 8; ++j)
            wr[j] = *reinterpret_cast<const float4*>(wrow + 4 * j);
#pragma unroll
        for (int j = 0; j < 2; ++j) {
            const int f  = j * 256 + t;
            const int cl = f & 31;
            const int q  = (f >> 5) & 15;
            pp[j] = *reinterpret_cast<const float4*>(
                P + (size_t)(cc0 + cl) * DIM + 4 * q);
        }
    };
    auto STAGE = [&](float4* wr, float4* pp, int cc0) {
        float* wrow = w + (pbase + t) * CELLS + cc0;
#pragma unroll
        for (int j = 0; j < 8; ++j) {
            float4 v = wr[j];
            v.x *= al; v.y *= al; v.z *= al; v.w *= al;
            *reinterpret_cast<float4*>(wrow + 4 * j) = v;   // final w2
#pragma unroll
            for (int jj = 0; jj < 4; ++jj) {
                const int r = 4 * j + jj;
                wT[r * 256 + 4 * ((t >> 2) ^ r) + (t & 3)] = (&v.x)[jj];
            }
        }
#pragma unroll
        for (int j = 0; j < 2; ++j) {
            const int f  = j * 256 + t;
            const int cl = f & 31;
            const int q  = (f >> 5) & 15;
            *reinterpret_cast<float4*>(&Pt[cl * 64 + 4 * (q ^ (cl & 15))]) = pp[j];
        }
    };
    auto KLOOP = [&]() {
#pragma unroll 4
        for (int k = 0; k < 32; ++k) {
            const float4 wf0 = *reinterpret_cast<const float4*>(
                &wT[k * 256 + 4 * (pr ^ k)]);
            const float4 wf1 = *reinterpret_cast<const float4*>(
                &wT[k * 256 + 4 * ((32 + pr) ^ k)]);
            const float4 pf0 = *reinterpret_cast<const float4*>(
                &Pt[k * 64 + 4 * ((2 * dr) ^ (k & 15))]);
            const float4 pf1 = *reinterpret_cast<const float4*>(
                &Pt[k * 64 + 4 * ((2 * dr + 1) ^ (k & 15))]);
#pragma unroll
            for (int i = 0; i < 4; ++i) {
                const float a = (&wf0.x)[i];
                const float b = (&wf1.x)[i];
#pragma unroll
                for (int j = 0; j < 4; ++j) {
                    const float p0 = (&pf0.x)[j];
                    const float p1 = (&pf1.x)[j];
                    acc[i][j]         = fmaf(a, p0, acc[i][j]);
                    acc[i][4 + j]     = fmaf(a, p1, acc[i][4 + j]);
                    acc[4 + i][j]     = fmaf(b, p0, acc[4 + i][j]);
                    acc[4 + i][4 + j] = fmaf(b, p1, acc[4 + i][4 + j]);
                }
            }
        }
    };

    float4 wA[8], pA[2], wB[8], pB[2];
    LOADW(wA, pA, 0);

#pragma unroll 1
    for (int cp = 0; cp < 4; ++cp) {
        STAGE(wA, pA, (2 * cp) * 32);
        __syncthreads();
        LOADW(wB, pB, (2 * cp + 1) * 32);   // prefetch under k-loop
        KLOOP();
        __syncthreads();
        STAGE(wB, pB, (2 * cp + 1) * 32);
        __syncthreads();
        if (cp < 3) LOADW(wA, pA, (2 * cp + 2) * 32);  // prefetch under k-loop
        KLOOP();
        __syncthreads();
    }

    // ---- blended store: thread's 8 pts x 8 dims ----
#pragma unroll
    for (int i = 0; i < 8; ++i) {
        const int p = ((i < 4) ? 0 : 128) + 4 * pr + (i & 3);
        float* orow = bl + (pbase + p) * DIM + 8 * dr;
        *reinterpret_cast<float4*>(orow) =
            make_float4(acc[i][0], acc[i][1], acc[i][2], acc[i][3]);
        *reinterpret_cast<float4*>(orow + 4) =
            make_float4(acc[i][4], acc[i][5], acc[i][6], acc[i][7]);
    }
}

extern "C" void kernel_launch(void* const* d_in, const int* in_sizes, int n_in,
                              void* d_out, int out_size, void* d_ws, size_t ws_size,
                              hipStream_t stream) {
    const float* x           = (const float*)d_in[0];
    const float* prototypes  = (const float*)d_in[1];
    const float* grid_pos    = (const float*)d_in[2];
    const float* gate_logits = (const float*)d_in[3];
    const float* temp_raw    = (const float*)d_in[4];
    float*       out         = (float*)d_out;
    float*       blended     = out;                           // [N, 64]
    float*       w           = out + (size_t)N_PTS * DIM;     // [N, 256]
    float*       ws          = (float*)d_ws;
    float*       alpha       = ws + WS_ALPHA;                 // N floats

    (void)hipFuncSetAttribute((const void*)dist_kernel,
                              hipFuncAttributeMaxDynamicSharedMemorySize, 69632);

    prep_kernel<<<1, CELLS, 0, stream>>>(prototypes, grid_pos, gate_logits,
                                         temp_raw, ws);
    dist_kernel<<<N_PTS / 128, 256, 68096, stream>>>(x, prototypes, grid_pos,
                                                     ws, w, alpha);
    blend_kernel<<<N_PTS / 256, 256, 40960, stream>>>(w, prototypes, alpha,
                                                      blended);
}